// Round 1
// baseline (139.578 us; speedup 1.0000x reference)
//
#include <hip/hip_runtime.h>

#define NB   8
#define S_   1024
#define DIN  1280
#define RANK 64
#define DOUT 1280
#define DOWN (RANK * DIN)          // 81920
#define EMB  (DOWN + DOUT * RANK)  // 163840

typedef __bf16 bf16x8 __attribute__((ext_vector_type(8)));
typedef float  f32x4  __attribute__((ext_vector_type(4)));

__device__ __forceinline__ bf16x8 cvt8(float4 a, float4 b) {
    bf16x8 r;
    r[0] = (__bf16)a.x; r[1] = (__bf16)a.y; r[2] = (__bf16)a.z; r[3] = (__bf16)a.w;
    r[4] = (__bf16)b.x; r[5] = (__bf16)b.y; r[6] = (__bf16)b.z; r[7] = (__bf16)b.w;
    return r;
}

// One WG = (batch b, 32 rows of S). 8 waves: wave w -> m-tile (w&1), K1 n-tile (w>>1).
// K1: h[32,64] = x[32,1280] @ w_down[64,1280]^T   (40 MFMA k-steps)
// K2: out[32,1280] = h[32,64] @ w_up[1280,64]^T   (80 n-tiles x 2 k-steps)
__global__ __launch_bounds__(512) void lora_fused(const float* __restrict__ x,
                                                  const float* __restrict__ embed,
                                                  float* __restrict__ out) {
    // h handoff: rows padded 64->72 bf16 so ds_read_b128 rows land 4 banks apart (2-way, free)
    __shared__ __bf16 hs[32][72];

    const int b    = blockIdx.x & 7;          // round-robin dispatch -> batch pinned per XCD
    const int s0   = (blockIdx.x >> 3) * 32;
    const int w    = threadIdx.x >> 6;        // wave 0..7
    const int l    = threadIdx.x & 63;
    const int quad = l >> 4;                  // 0..3
    const int lc   = l & 15;
    const int mt   = w & 1;                   // m-tile 0..1
    const int nt   = w >> 1;                  // K1 n-tile 0..3
    const int dq   = quad * 8;                // per-lane k offset within a 32-wide k-step

    // ---------------- K1: h = x @ w_down^T ----------------
    // A-frag: A[m=lc][k = kstep*32 + dq + j]  from x row (s0+mt*16+lc)
    // B-frag: B[n=lc][k]                      from w_down row (nt*16+lc)  (both K-contiguous)
    const float* xrow  = x + (size_t)((b * S_) + s0 + mt * 16 + lc) * DIN;
    const float* wdrow = embed + (size_t)b * EMB + (size_t)(nt * 16 + lc) * DIN;

    f32x4 acc = {0.f, 0.f, 0.f, 0.f};
#pragma unroll 4
    for (int k = 0; k < 40; ++k) {
        const int d = k * 32 + dq;
        const float4* pa = reinterpret_cast<const float4*>(xrow + d);
        const float4* pb = reinterpret_cast<const float4*>(wdrow + d);
        float4 a0 = pa[0], a1 = pa[1];
        float4 b0 = pb[0], b1 = pb[1];
        bf16x8 af = cvt8(a0, a1);
        bf16x8 bf = cvt8(b0, b1);
        acc = __builtin_amdgcn_mfma_f32_16x16x32_bf16(af, bf, acc, 0, 0, 0);
    }

    // C/D layout: D[row = quad*4+i][col = lc]  ->  h[s-in-tile][r-in-tile]
#pragma unroll
    for (int i = 0; i < 4; ++i)
        hs[mt * 16 + quad * 4 + i][nt * 16 + lc] = (__bf16)acc[i];

    __syncthreads();

    // ---------------- K2: out = h @ w_up^T ----------------
    // A-frags (reused across all 80 n-tiles): A[m=lc][k = k0*32 + dq + j] from hs
    bf16x8 ha0 = *reinterpret_cast<const bf16x8*>(&hs[mt * 16 + lc][dq]);        // k0=0: r in [0,32)
    bf16x8 ha1 = *reinterpret_cast<const bf16x8*>(&hs[mt * 16 + lc][32 + dq]);   // k0=1: r in [32,64)

    const float* wub   = embed + (size_t)b * EMB + DOWN;   // w_up[o][r], r contiguous
    float*       obase = out + (size_t)((b * S_) + s0 + mt * 16) * DOUT;

#pragma unroll 2
    for (int t = 0; t < 20; ++t) {
        const int n = (w >> 1) + 4 * t;    // n-tile 0..79, each handled by 2 waves (m=0,1)
        const int o = n * 16 + lc;
        const float* wrow = wub + (size_t)o * RANK;
        const float4* p0 = reinterpret_cast<const float4*>(wrow + dq);        // k0=0
        const float4* p1 = reinterpret_cast<const float4*>(wrow + 32 + dq);   // k0=1
        float4 w0 = p0[0], w1 = p0[1];
        float4 w2 = p1[0], w3 = p1[1];
        bf16x8 bw0 = cvt8(w0, w1);
        bf16x8 bw1 = cvt8(w2, w3);

        f32x4 c = {0.f, 0.f, 0.f, 0.f};
        c = __builtin_amdgcn_mfma_f32_16x16x32_bf16(ha0, bw0, c, 0, 0, 0);
        c = __builtin_amdgcn_mfma_f32_16x16x32_bf16(ha1, bw1, c, 0, 0, 0);

        // D[row=quad*4+i][col=lc] -> out[b, s0 + mt*16 + quad*4 + i, n*16 + lc]
        float* op = obase + (size_t)(quad * 4) * DOUT + n * 16 + lc;
#pragma unroll
        for (int i = 0; i < 4; ++i)
            op[(size_t)i * DOUT] = c[i];
    }
}

extern "C" void kernel_launch(void* const* d_in, const int* in_sizes, int n_in,
                              void* d_out, int out_size, void* d_ws, size_t ws_size,
                              hipStream_t stream) {
    const float* x     = (const float*)d_in[0];
    const float* embed = (const float*)d_in[1];
    float*       out   = (float*)d_out;
    (void)in_sizes; (void)n_in; (void)out_size; (void)d_ws; (void)ws_size;

    // 256 WGs (8 batches x 32 s-tiles of 32 rows), 512 threads (8 waves)
    lora_fused<<<dim3(256), dim3(512), 0, stream>>>(x, embed, out);
}

// Round 2
// 133.290 us; speedup vs baseline: 1.0472x; 1.0472x over previous
//
#include <hip/hip_runtime.h>

#define NB   8
#define S_   1024
#define DIN  1280
#define RANK 64
#define DOUT 1280
#define DOWN (RANK * DIN)          // 81920
#define EMB  (DOWN + DOUT * RANK)  // 163840

typedef __bf16 bf16x8 __attribute__((ext_vector_type(8)));
typedef __bf16 bf16x4 __attribute__((ext_vector_type(4)));
typedef float  f32x4  __attribute__((ext_vector_type(4)));

__device__ __forceinline__ bf16x8 cvt8(float4 a, float4 b) {
    bf16x8 r;
    r[0] = (__bf16)a.x; r[1] = (__bf16)a.y; r[2] = (__bf16)a.z; r[3] = (__bf16)a.w;
    r[4] = (__bf16)b.x; r[5] = (__bf16)b.y; r[6] = (__bf16)b.z; r[7] = (__bf16)b.w;
    return r;
}

// ---------------- Kernel A: h[b,s,64] = x[b,s,:] @ w_down[b]^T ----------------
// Grid 512 = 8 batches x 64 s-tiles (16 rows). 4 waves split K (10 k-steps each),
// each wave keeps 4 INDEPENDENT acc chains (one per 16-wide n-tile) -> deep ILP,
// 10x16B loads per k-step batched in one vmcnt window. LDS fp32 reduce, bf16 out.
__global__ __launch_bounds__(256) void lora_down(const float* __restrict__ x,
                                                 const float* __restrict__ embed,
                                                 __bf16* __restrict__ h) {
    __shared__ float pbuf[4][16][68];   // stride 68: worst 2-way bank alias (free)

    const int b    = blockIdx.x & 7;          // batch pinned per XCD
    const int s0   = (blockIdx.x >> 3) * 16;
    const int w    = threadIdx.x >> 6;        // wave 0..3 -> k-chunk
    const int l    = threadIdx.x & 63;
    const int quad = l >> 4;
    const int lc   = l & 15;
    const int dq   = quad * 8;

    const float* xrow = x + (size_t)(b * S_ + s0 + lc) * DIN;
    const float* wd0  = embed + (size_t)b * EMB + (size_t)(lc)      * DIN;
    const float* wd1  = embed + (size_t)b * EMB + (size_t)(16 + lc) * DIN;
    const float* wd2  = embed + (size_t)b * EMB + (size_t)(32 + lc) * DIN;
    const float* wd3  = embed + (size_t)b * EMB + (size_t)(48 + lc) * DIN;

    f32x4 acc0 = {0,0,0,0}, acc1 = {0,0,0,0}, acc2 = {0,0,0,0}, acc3 = {0,0,0,0};

#pragma unroll 2
    for (int ks = 0; ks < 10; ++ks) {
        const int d = (w * 10 + ks) * 32 + dq;
        const float4* pa = reinterpret_cast<const float4*>(xrow + d);
        const float4* p0 = reinterpret_cast<const float4*>(wd0 + d);
        const float4* p1 = reinterpret_cast<const float4*>(wd1 + d);
        const float4* p2 = reinterpret_cast<const float4*>(wd2 + d);
        const float4* p3 = reinterpret_cast<const float4*>(wd3 + d);
        float4 a0 = pa[0], a1 = pa[1];
        float4 b00 = p0[0], b01 = p0[1];
        float4 b10 = p1[0], b11 = p1[1];
        float4 b20 = p2[0], b21 = p2[1];
        float4 b30 = p3[0], b31 = p3[1];
        bf16x8 af = cvt8(a0, a1);
        acc0 = __builtin_amdgcn_mfma_f32_16x16x32_bf16(af, cvt8(b00, b01), acc0, 0, 0, 0);
        acc1 = __builtin_amdgcn_mfma_f32_16x16x32_bf16(af, cvt8(b10, b11), acc1, 0, 0, 0);
        acc2 = __builtin_amdgcn_mfma_f32_16x16x32_bf16(af, cvt8(b20, b21), acc2, 0, 0, 0);
        acc3 = __builtin_amdgcn_mfma_f32_16x16x32_bf16(af, cvt8(b30, b31), acc3, 0, 0, 0);
    }

#pragma unroll
    for (int i = 0; i < 4; ++i) {
        pbuf[w][quad * 4 + i][lc]      = acc0[i];
        pbuf[w][quad * 4 + i][16 + lc] = acc1[i];
        pbuf[w][quad * 4 + i][32 + lc] = acc2[i];
        pbuf[w][quad * 4 + i][48 + lc] = acc3[i];
    }
    __syncthreads();

    // reduce 4 partials, write h tile (fully coalesced 8B/thread)
    const int row = threadIdx.x >> 4;          // 0..15
    const int c4  = (threadIdx.x & 15) * 4;    // 0..60
    f32x4 s = *reinterpret_cast<const f32x4*>(&pbuf[0][row][c4]);
    s = s + *reinterpret_cast<const f32x4*>(&pbuf[1][row][c4]);
    s = s + *reinterpret_cast<const f32x4*>(&pbuf[2][row][c4]);
    s = s + *reinterpret_cast<const f32x4*>(&pbuf[3][row][c4]);
    bf16x4 hv;
    hv[0] = (__bf16)s[0]; hv[1] = (__bf16)s[1]; hv[2] = (__bf16)s[2]; hv[3] = (__bf16)s[3];
    *reinterpret_cast<bf16x4*>(h + (size_t)(b * S_ + s0 + row) * RANK + c4) = hv;
}

// ---------------- Kernel B: out[b,s,:] = h[b,s,:] @ w_up[b]^T ----------------
// Grid 1280 = 8 batches x 32 s-tiles (32 rows) x 5 n-chunks (256 outs). 512 thr
// -> ~4 blocks/CU (32 waves/CU). Per wave: 4 independent n-tile chains. h and
// w_up slices are L2-resident; kernel is write-bound.
__global__ __launch_bounds__(512) void lora_up(const __bf16* __restrict__ h,
                                               const float* __restrict__ embed,
                                               float* __restrict__ out) {
    const int b    = blockIdx.x & 7;
    const int rest = blockIdx.x >> 3;         // 0..159
    const int st   = rest & 31;               // s-tile (32 rows)
    const int nc   = rest >> 5;               // 0..4
    const int w    = threadIdx.x >> 6;        // wave 0..7
    const int l    = threadIdx.x & 63;
    const int quad = l >> 4;
    const int lc   = l & 15;
    const int dq   = quad * 8;
    const int mt   = w & 1;                   // m-tile 0..1
    const int ng   = w >> 1;                  // n-group 0..3

    const __bf16* hrow = h + (size_t)(b * S_ + st * 32 + mt * 16 + lc) * RANK;
    bf16x8 ha0 = *reinterpret_cast<const bf16x8*>(hrow + dq);
    bf16x8 ha1 = *reinterpret_cast<const bf16x8*>(hrow + 32 + dq);

    const float* wub = embed + (size_t)b * EMB + DOWN;
    float* ob = out + (size_t)(b * S_ + st * 32 + mt * 16 + quad * 4) * DOUT;

#pragma unroll
    for (int j = 0; j < 4; ++j) {
        const int o = nc * 256 + (ng * 4 + j) * 16 + lc;
        const float4* p = reinterpret_cast<const float4*>(wub + (size_t)o * RANK + dq);
        const float4* q = reinterpret_cast<const float4*>(wub + (size_t)o * RANK + 32 + dq);
        float4 w0 = p[0], w1 = p[1], w2 = q[0], w3 = q[1];
        f32x4 c = {0,0,0,0};
        c = __builtin_amdgcn_mfma_f32_16x16x32_bf16(ha0, cvt8(w0, w1), c, 0, 0, 0);
        c = __builtin_amdgcn_mfma_f32_16x16x32_bf16(ha1, cvt8(w2, w3), c, 0, 0, 0);
#pragma unroll
        for (int i = 0; i < 4; ++i)
            ob[(size_t)i * DOUT + o] = c[i];
    }
}

extern "C" void kernel_launch(void* const* d_in, const int* in_sizes, int n_in,
                              void* d_out, int out_size, void* d_ws, size_t ws_size,
                              hipStream_t stream) {
    const float* x     = (const float*)d_in[0];
    const float* embed = (const float*)d_in[1];
    float*       out   = (float*)d_out;
    __bf16*      h     = (__bf16*)d_ws;   // 8*1024*64 bf16 = 1 MB
    (void)in_sizes; (void)n_in; (void)out_size; (void)ws_size;

    lora_down<<<dim3(512), dim3(256), 0, stream>>>(x, embed, h);
    lora_up<<<dim3(1280), dim3(512), 0, stream>>>(h, embed, out);
}

// Round 3
// 128.582 us; speedup vs baseline: 1.0855x; 1.0366x over previous
//
#include <hip/hip_runtime.h>

#define NB   8
#define S_   1024
#define DIN  1280
#define RANK 64
#define DOUT 1280
#define DOWN (RANK * DIN)          // 81920
#define EMB  (DOWN + DOUT * RANK)  // 163840

typedef __bf16 bf16x8 __attribute__((ext_vector_type(8)));
typedef float  f32x4  __attribute__((ext_vector_type(4)));

__device__ __forceinline__ bf16x8 cvt8(float4 a, float4 b) {
    bf16x8 r;
    r[0] = (__bf16)a.x; r[1] = (__bf16)a.y; r[2] = (__bf16)a.z; r[3] = (__bf16)a.w;
    r[4] = (__bf16)b.x; r[5] = (__bf16)b.y; r[6] = (__bf16)b.z; r[7] = (__bf16)b.w;
    return r;
}

// One WG = (batch b, 16 rows of S). 8 waves, 2 blocks/CU (16 waves/CU).
// Phase 1 (down): waves split K 8-way (5 k-steps each), 4 independent acc
//   chains per wave, LDS tree-reduce -> h tile (16x64 bf16) stays in LDS.
// Phase 2 (up): waves split N 8-way (10 n-tiles each), w_up from L2.
__global__ __launch_bounds__(512, 4) void lora_fused(const float* __restrict__ x,
                                                     const float* __restrict__ embed,
                                                     float* __restrict__ out) {
    __shared__ __align__(16) float  pbuf[8][16][68];  // 34.8 KB partials
    __shared__ __align__(16) __bf16 hld[16][80];      // 2.5 KB h tile (pad 64->80)

    const int b    = blockIdx.x & 7;
    const int s0   = (blockIdx.x >> 3) * 16;
    const int w    = threadIdx.x >> 6;        // wave 0..7
    const int l    = threadIdx.x & 63;
    const int quad = l >> 4;
    const int lc   = l & 15;
    const int dq   = quad * 8;

    // ---------------- Phase 1: h = x @ w_down^T (k-split 8) ----------------
    const float* xrow = x + (size_t)(b * S_ + s0 + lc) * DIN + w * 160;
    const float* wdb  = embed + (size_t)b * EMB + w * 160;
    const float* wd0  = wdb + (size_t)(lc)      * DIN;
    const float* wd1  = wdb + (size_t)(16 + lc) * DIN;
    const float* wd2  = wdb + (size_t)(32 + lc) * DIN;
    const float* wd3  = wdb + (size_t)(48 + lc) * DIN;

    f32x4 acc0 = {0,0,0,0}, acc1 = {0,0,0,0}, acc2 = {0,0,0,0}, acc3 = {0,0,0,0};

#pragma unroll
    for (int ks = 0; ks < 5; ++ks) {
        const int d = ks * 32 + dq;
        const float4* pa = reinterpret_cast<const float4*>(xrow + d);
        const float4* p0 = reinterpret_cast<const float4*>(wd0 + d);
        const float4* p1 = reinterpret_cast<const float4*>(wd1 + d);
        const float4* p2 = reinterpret_cast<const float4*>(wd2 + d);
        const float4* p3 = reinterpret_cast<const float4*>(wd3 + d);
        float4 a0 = pa[0], a1 = pa[1];
        float4 b00 = p0[0], b01 = p0[1];
        float4 b10 = p1[0], b11 = p1[1];
        float4 b20 = p2[0], b21 = p2[1];
        float4 b30 = p3[0], b31 = p3[1];
        bf16x8 af = cvt8(a0, a1);
        acc0 = __builtin_amdgcn_mfma_f32_16x16x32_bf16(af, cvt8(b00, b01), acc0, 0, 0, 0);
        acc1 = __builtin_amdgcn_mfma_f32_16x16x32_bf16(af, cvt8(b10, b11), acc1, 0, 0, 0);
        acc2 = __builtin_amdgcn_mfma_f32_16x16x32_bf16(af, cvt8(b20, b21), acc2, 0, 0, 0);
        acc3 = __builtin_amdgcn_mfma_f32_16x16x32_bf16(af, cvt8(b30, b31), acc3, 0, 0, 0);
    }

#pragma unroll
    for (int i = 0; i < 4; ++i) {
        pbuf[w][quad * 4 + i][lc]      = acc0[i];
        pbuf[w][quad * 4 + i][16 + lc] = acc1[i];
        pbuf[w][quad * 4 + i][32 + lc] = acc2[i];
        pbuf[w][quad * 4 + i][48 + lc] = acc3[i];
    }
    __syncthreads();

    // reduce 8 partials -> h tile in LDS (bf16)
    if (threadIdx.x < 256) {
        const int row = threadIdx.x >> 4;
        const int c4  = (threadIdx.x & 15) * 4;
        f32x4 s = *reinterpret_cast<const f32x4*>(&pbuf[0][row][c4]);
#pragma unroll
        for (int k = 1; k < 8; ++k)
            s = s + *reinterpret_cast<const f32x4*>(&pbuf[k][row][c4]);
#pragma unroll
        for (int j = 0; j < 4; ++j)
            hld[row][c4 + j] = (__bf16)s[j];
    }
    __syncthreads();

    // ---------------- Phase 2: out = h @ w_up^T (n-split 8) ----------------
    bf16x8 ha0 = *reinterpret_cast<const bf16x8*>(&hld[lc][dq]);
    bf16x8 ha1 = *reinterpret_cast<const bf16x8*>(&hld[lc][32 + dq]);

    const float* wub   = embed + (size_t)b * EMB + DOWN;
    float*       obase = out + (size_t)(b * S_ + s0 + quad * 4) * DOUT;

#pragma unroll 2
    for (int t = 0; t < 10; ++t) {
        const int n = w + 8 * t;                   // n-tile 0..79
        const int o = n * 16 + lc;
        const float4* p = reinterpret_cast<const float4*>(wub + (size_t)o * RANK + dq);
        const float4* q = reinterpret_cast<const float4*>(wub + (size_t)o * RANK + 32 + dq);
        float4 w0 = p[0], w1 = p[1], w2 = q[0], w3 = q[1];
        f32x4 c = {0,0,0,0};
        c = __builtin_amdgcn_mfma_f32_16x16x32_bf16(ha0, cvt8(w0, w1), c, 0, 0, 0);
        c = __builtin_amdgcn_mfma_f32_16x16x32_bf16(ha1, cvt8(w2, w3), c, 0, 0, 0);
#pragma unroll
        for (int i = 0; i < 4; ++i)
            obase[(size_t)i * DOUT + n * 16 + lc] = c[i];
    }
}

extern "C" void kernel_launch(void* const* d_in, const int* in_sizes, int n_in,
                              void* d_out, int out_size, void* d_ws, size_t ws_size,
                              hipStream_t stream) {
    const float* x     = (const float*)d_in[0];
    const float* embed = (const float*)d_in[1];
    float*       out   = (float*)d_out;
    (void)in_sizes; (void)n_in; (void)out_size; (void)d_ws; (void)ws_size;

    // 512 WGs (8 batches x 64 s-tiles of 16 rows), 512 threads (8 waves)
    lora_fused<<<dim3(512), dim3(512), 0, stream>>>(x, embed, out);
}

// Round 4
// 128.189 us; speedup vs baseline: 1.0888x; 1.0031x over previous
//
#include <hip/hip_runtime.h>

#define NB   8
#define S_   1024
#define DIN  1280
#define RANK 64
#define DOUT 1280
#define DOWN (RANK * DIN)          // 81920
#define EMB  (DOWN + DOUT * RANK)  // 163840

typedef __bf16 bf16x8 __attribute__((ext_vector_type(8)));
typedef float  f32x4  __attribute__((ext_vector_type(4)));

__device__ __forceinline__ bf16x8 cvt8(float4 a, float4 b) {
    bf16x8 r;
    r[0] = (__bf16)a.x; r[1] = (__bf16)a.y; r[2] = (__bf16)a.z; r[3] = (__bf16)a.w;
    r[4] = (__bf16)b.x; r[5] = (__bf16)b.y; r[6] = (__bf16)b.z; r[7] = (__bf16)b.w;
    return r;
}

struct Stage1 {                       // one k-step of phase 1: 10 float4 = 40 VGPR
    float4 a0, a1, b00, b01, b10, b11, b20, b21, b30, b31;
};
struct Stage2 {                       // one n-tile of phase 2: 4 float4 = 16 VGPR
    float4 w0, w1, w2, w3;
};

// One WG = (batch b, 16 rows of S). 8 waves, grid 512 -> 2 blocks/CU.
// Phase 1: k-split 8 (5 k-steps/wave), register double-buffered loads.
// Phase 2: n-split 8 (10 n-tiles/wave), prefetch depth 2.
__global__ __launch_bounds__(512, 4) void lora_fused(const float* __restrict__ x,
                                                     const float* __restrict__ embed,
                                                     float* __restrict__ out) {
    __shared__ __align__(16) float  pbuf[8][16][68];
    __shared__ __align__(16) __bf16 hld[16][80];

    const int b    = blockIdx.x & 7;
    const int s0   = (blockIdx.x >> 3) * 16;
    const int w    = threadIdx.x >> 6;
    const int l    = threadIdx.x & 63;
    const int quad = l >> 4;
    const int lc   = l & 15;
    const int dq   = quad * 8;

    // ---------------- Phase 1: h = x @ w_down^T (k-split 8) ----------------
    const float* xrow = x + (size_t)(b * S_ + s0 + lc) * DIN + w * 160;
    const float* wdb  = embed + (size_t)b * EMB + w * 160;
    const float* wd0  = wdb + (size_t)(lc)      * DIN;
    const float* wd1  = wdb + (size_t)(16 + lc) * DIN;
    const float* wd2  = wdb + (size_t)(32 + lc) * DIN;
    const float* wd3  = wdb + (size_t)(48 + lc) * DIN;

    f32x4 acc0 = {0,0,0,0}, acc1 = {0,0,0,0}, acc2 = {0,0,0,0}, acc3 = {0,0,0,0};

    auto LD1 = [&](Stage1& s, int ks) {
        const int d = ks * 32 + dq;
        const float4* pa = reinterpret_cast<const float4*>(xrow + d);
        const float4* p0 = reinterpret_cast<const float4*>(wd0 + d);
        const float4* p1 = reinterpret_cast<const float4*>(wd1 + d);
        const float4* p2 = reinterpret_cast<const float4*>(wd2 + d);
        const float4* p3 = reinterpret_cast<const float4*>(wd3 + d);
        s.a0 = pa[0]; s.a1 = pa[1];
        s.b00 = p0[0]; s.b01 = p0[1];
        s.b10 = p1[0]; s.b11 = p1[1];
        s.b20 = p2[0]; s.b21 = p2[1];
        s.b30 = p3[0]; s.b31 = p3[1];
    };
    auto FMA1 = [&](const Stage1& s) {
        bf16x8 af = cvt8(s.a0, s.a1);
        acc0 = __builtin_amdgcn_mfma_f32_16x16x32_bf16(af, cvt8(s.b00, s.b01), acc0, 0, 0, 0);
        acc1 = __builtin_amdgcn_mfma_f32_16x16x32_bf16(af, cvt8(s.b10, s.b11), acc1, 0, 0, 0);
        acc2 = __builtin_amdgcn_mfma_f32_16x16x32_bf16(af, cvt8(s.b20, s.b21), acc2, 0, 0, 0);
        acc3 = __builtin_amdgcn_mfma_f32_16x16x32_bf16(af, cvt8(s.b30, s.b31), acc3, 0, 0, 0);
    };

    {
        Stage1 s0v, s1v;
        LD1(s0v, 0);
        LD1(s1v, 1);
        FMA1(s0v);          // waits only on s0v's 10 loads; s1v stays in flight
        LD1(s0v, 2);
        FMA1(s1v);
        LD1(s1v, 3);
        FMA1(s0v);
        LD1(s0v, 4);
        FMA1(s1v);
        FMA1(s0v);
    }

#pragma unroll
    for (int i = 0; i < 4; ++i) {
        pbuf[w][quad * 4 + i][lc]      = acc0[i];
        pbuf[w][quad * 4 + i][16 + lc] = acc1[i];
        pbuf[w][quad * 4 + i][32 + lc] = acc2[i];
        pbuf[w][quad * 4 + i][48 + lc] = acc3[i];
    }
    __syncthreads();

    if (threadIdx.x < 256) {
        const int row = threadIdx.x >> 4;
        const int c4  = (threadIdx.x & 15) * 4;
        f32x4 s = *reinterpret_cast<const f32x4*>(&pbuf[0][row][c4]);
#pragma unroll
        for (int k = 1; k < 8; ++k)
            s = s + *reinterpret_cast<const f32x4*>(&pbuf[k][row][c4]);
#pragma unroll
        for (int j = 0; j < 4; ++j)
            hld[row][c4 + j] = (__bf16)s[j];
    }
    __syncthreads();

    // ---------------- Phase 2: out = h @ w_up^T (n-split 8) ----------------
    bf16x8 ha0 = *reinterpret_cast<const bf16x8*>(&hld[lc][dq]);
    bf16x8 ha1 = *reinterpret_cast<const bf16x8*>(&hld[lc][32 + dq]);

    const float* wub   = embed + (size_t)b * EMB + DOWN;
    float*       obase = out + (size_t)(b * S_ + s0 + quad * 4) * DOUT;

    auto LD2 = [&](Stage2& s, int t) {
        const int o = (w + 8 * t) * 16 + lc;
        const float4* p = reinterpret_cast<const float4*>(wub + (size_t)o * RANK + dq);
        const float4* q = reinterpret_cast<const float4*>(wub + (size_t)o * RANK + 32 + dq);
        s.w0 = p[0]; s.w1 = p[1]; s.w2 = q[0]; s.w3 = q[1];
    };
    auto FMA2 = [&](const Stage2& s, int t) {
        f32x4 c = {0,0,0,0};
        c = __builtin_amdgcn_mfma_f32_16x16x32_bf16(ha0, cvt8(s.w0, s.w1), c, 0, 0, 0);
        c = __builtin_amdgcn_mfma_f32_16x16x32_bf16(ha1, cvt8(s.w2, s.w3), c, 0, 0, 0);
        const int n = w + 8 * t;
#pragma unroll
        for (int i = 0; i < 4; ++i)
            obase[(size_t)i * DOUT + n * 16 + lc] = c[i];
    };

    {
        Stage2 t0v, t1v;
        LD2(t0v, 0);
        LD2(t1v, 1);
#pragma unroll
        for (int t = 0; t < 10; ++t) {
            if (t & 1) {
                FMA2(t1v, t);
                if (t + 2 < 10) LD2(t1v, t + 2);
            } else {
                FMA2(t0v, t);
                if (t + 2 < 10) LD2(t0v, t + 2);
            }
        }
    }
}

extern "C" void kernel_launch(void* const* d_in, const int* in_sizes, int n_in,
                              void* d_out, int out_size, void* d_ws, size_t ws_size,
                              hipStream_t stream) {
    const float* x     = (const float*)d_in[0];
    const float* embed = (const float*)d_in[1];
    float*       out   = (float*)d_out;
    (void)in_sizes; (void)n_in; (void)out_size; (void)d_ws; (void)ws_size;

    lora_fused<<<dim3(512), dim3(512), 0, stream>>>(x, embed, out);
}

// Round 5
// 109.347 us; speedup vs baseline: 1.2765x; 1.1723x over previous
//
#include <hip/hip_runtime.h>

#define NB   8
#define S_   1024
#define DIN  1280
#define RANK 64
#define DOUT 1280
#define DOWN (RANK * DIN)          // 81920
#define EMB  (DOWN + DOUT * RANK)  // 163840
#define XSTRIDE 1288               // x LDS row stride (bf16): 2576B, 16B-aligned, +4 banks/row

typedef __bf16 bf16x8 __attribute__((ext_vector_type(8)));
typedef __bf16 bf16x4 __attribute__((ext_vector_type(4)));
typedef float  f32x4  __attribute__((ext_vector_type(4)));

// ---------------- prep: embed fp32 -> bf16 (into d_ws) ----------------
__global__ __launch_bounds__(256) void cvt_embed(const float* __restrict__ src,
                                                 __bf16* __restrict__ dst, int n8) {
    const int i = blockIdx.x * 256 + threadIdx.x;
    if (i < n8) {
        const float4* s = reinterpret_cast<const float4*>(src) + (size_t)i * 2;
        float4 f0 = s[0], f1 = s[1];
        bf16x8 v;
        v[0]=(__bf16)f0.x; v[1]=(__bf16)f0.y; v[2]=(__bf16)f0.z; v[3]=(__bf16)f0.w;
        v[4]=(__bf16)f1.x; v[5]=(__bf16)f1.y; v[6]=(__bf16)f1.z; v[7]=(__bf16)f1.w;
        *reinterpret_cast<bf16x8*>(dst + (size_t)i * 8) = v;
    }
}

// ---------------- main: one WG = (batch b, 16 rows of S) ----------------
// Stage x tile fp32->bf16 in LDS (coalesced). All fragment loads are bf16:
// 16B/lane with adjacent quads -> 16 segments/instr instead of 64.
// Phase 1: waves (nt 0..3, kh 0..1), 20 k-steps each, LDS pair-reduce.
// Phase 2: n-split 8, w_up bf16 direct (L2-hot).
__global__ __launch_bounds__(512, 2) void lora_main(const float* __restrict__ x,
                                                    const __bf16* __restrict__ ew,
                                                    float* __restrict__ out) {
    __shared__ __bf16 xls[16 * XSTRIDE];   // 41.2 KB bf16 x tile
    __shared__ float  pbuf[4][16][20];     // 5.1 KB  kh-reduce
    __shared__ __bf16 hld[16][80];         // 2.6 KB  h tile

    const int b    = blockIdx.x & 7;           // batch pinned per XCD
    const int s0   = (blockIdx.x >> 3) * 16;
    const int t    = threadIdx.x;
    const int w    = t >> 6;
    const int l    = t & 63;
    const int quad = l >> 4;
    const int lc   = l & 15;
    const int dq   = quad * 8;

    // ---- stage x tile: 16 rows x 1280 fp32, fully coalesced, cvt to bf16 ----
    {
        const int row = t >> 5;                // 0..15 (32 threads per row)
        const int c   = t & 31;                // float4 index within row chunk
        const float4* src = reinterpret_cast<const float4*>(x + (size_t)(b * S_ + s0 + row) * DIN);
        __bf16* drow = xls + row * XSTRIDE;
#pragma unroll
        for (int j = 0; j < 10; ++j) {
            float4 f = src[c + 32 * j];
            bf16x4 v;
            v[0]=(__bf16)f.x; v[1]=(__bf16)f.y; v[2]=(__bf16)f.z; v[3]=(__bf16)f.w;
            *reinterpret_cast<bf16x4*>(drow + c * 4 + 128 * j) = v;
        }
    }
    __syncthreads();

    // ---- phase 1: h = x @ w_down^T ----
    const int nt = w & 3;                      // n-tile (16 of 64 ranks)
    const int kh = w >> 2;                     // K half (640 each)
    const __bf16* wdrow  = ew + (size_t)b * EMB + (size_t)(nt * 16 + lc) * DIN + kh * 640;
    const __bf16* xlsrow = xls + lc * XSTRIDE + kh * 640;

    f32x4 acc = {0,0,0,0};
#pragma unroll 5
    for (int ks = 0; ks < 20; ++ks) {
        const int k = ks * 32 + dq;
        bf16x8 af = *reinterpret_cast<const bf16x8*>(xlsrow + k);   // ds_read_b128
        bf16x8 bf = *reinterpret_cast<const bf16x8*>(wdrow + k);    // 16-seg global
        acc = __builtin_amdgcn_mfma_f32_16x16x32_bf16(af, bf, acc, 0, 0, 0);
    }

    if (kh == 1) {
#pragma unroll
        for (int i = 0; i < 4; ++i) pbuf[nt][quad * 4 + i][lc] = acc[i];
    }
    __syncthreads();
    if (kh == 0) {
#pragma unroll
        for (int i = 0; i < 4; ++i) {
            float v = acc[i] + pbuf[nt][quad * 4 + i][lc];
            hld[quad * 4 + i][nt * 16 + lc] = (__bf16)v;
        }
    }
    __syncthreads();

    // ---- phase 2: out = h @ w_up^T (n-split 8) ----
    bf16x8 ha0 = *reinterpret_cast<const bf16x8*>(&hld[lc][dq]);
    bf16x8 ha1 = *reinterpret_cast<const bf16x8*>(&hld[lc][32 + dq]);
    const __bf16* wu    = ew + (size_t)b * EMB + DOWN;
    float*        obase = out + (size_t)(b * S_ + s0 + quad * 4) * DOUT;

#pragma unroll 2
    for (int tt = 0; tt < 10; ++tt) {
        const int n = w + 8 * tt;
        const int o = n * 16 + lc;
        bf16x8 b0 = *reinterpret_cast<const bf16x8*>(wu + (size_t)o * RANK + dq);
        bf16x8 b1 = *reinterpret_cast<const bf16x8*>(wu + (size_t)o * RANK + 32 + dq);
        f32x4 c = {0,0,0,0};
        c = __builtin_amdgcn_mfma_f32_16x16x32_bf16(ha0, b0, c, 0, 0, 0);
        c = __builtin_amdgcn_mfma_f32_16x16x32_bf16(ha1, b1, c, 0, 0, 0);
#pragma unroll
        for (int i = 0; i < 4; ++i)
            obase[(size_t)i * DOUT + o] = c[i];
    }
}

extern "C" void kernel_launch(void* const* d_in, const int* in_sizes, int n_in,
                              void* d_out, int out_size, void* d_ws, size_t ws_size,
                              hipStream_t stream) {
    const float* x     = (const float*)d_in[0];
    const float* embed = (const float*)d_in[1];
    float*       out   = (float*)d_out;
    __bf16*      ew    = (__bf16*)d_ws;          // 8 x 163840 bf16 = 2.6 MB
    (void)in_sizes; (void)n_in; (void)out_size; (void)ws_size;

    // embed: 1,310,720 floats -> 163,840 groups of 8
    cvt_embed<<<dim3(640), dim3(256), 0, stream>>>(embed, ew, NB * EMB / 8);
    lora_main<<<dim3(512), dim3(512), 0, stream>>>(x, ew, out);
}